// Round 12
// baseline (332.778 us; speedup 1.0000x reference)
//
#include <hip/hip_runtime.h>
#include <math.h>

#define BATCH 32

// ---------------------------------------------------------------- utilities
__device__ __forceinline__ float eluf(float v) { return v > 0.f ? v : expm1f(v); }
__device__ __forceinline__ float softplusf(float x) {
    return fmaxf(x, 0.f) + log1pf(expf(-fabsf(x)));
}
__device__ __forceinline__ float sigmoidf(float x) { return 1.f / (1.f + expf(-x)); }

// async global->LDS, 16B per lane. LDS dest = wave-uniform base + lane*16;
// global source is per-lane. No VGPR round-trip (the R7..R11 serialization
// killer). Compiler never auto-emits this.
__device__ __forceinline__ void gload16(const float* g, float* l) {
    __builtin_amdgcn_global_load_lds(
        (const __attribute__((address_space(1))) void*)g,
        (__attribute__((address_space(3))) void*)l, 16, 0, 0);
}

// ---------------------------------------------------------------- weight transpose (all 4 layers, 1 launch)
// w[co][ci][3][3] -> wt[ci][co][9]: per ci a co-group's weights are contiguous
// dwords -> s_load_dwordx16 streams (R11-verified win).
__global__ __launch_bounds__(256) void wtrans_kernel(
    const float* __restrict__ w1, float* __restrict__ wt1,
    const float* __restrict__ w2, float* __restrict__ wt2,
    const float* __restrict__ w3, float* __restrict__ wt3,
    const float* __restrict__ w4, float* __restrict__ wt4)
{
    const int idx = blockIdx.x * 256 + threadIdx.x;
    const float* w; float* wt; int cin;
    switch (blockIdx.y) {
        case 0:  w = w1; wt = wt1; cin = 3;  break;
        case 1:  w = w2; wt = wt2; cin = 64; break;
        case 2:  w = w3; wt = wt3; cin = 64; break;
        default: w = w4; wt = wt4; cin = 64; break;
    }
    if (idx < cin * 576) {
        const int k = idx % 9, rest = idx / 9;
        const int co = rest & 63, ci = rest >> 6;
        wt[idx] = w[(co * cin + ci) * 9 + k];
    }
}

// ---------------------------------------------------------------- conv1: 3->64, G=64, transposed weights
__global__ __launch_bounds__(256, 2) void conv1_kernel(
    const float* __restrict__ in, const float* __restrict__ wt,
    const float* __restrict__ bias, float* __restrict__ out)
{
    const int b  = blockIdx.x;
    const int t  = threadIdx.x;
    const int px = blockIdx.z * 256 + t;
    const bool active = px < 63 * 63;
    const int p = active ? px : 0;
    const int y = p / 63, x = p % 63;

    const float* ib = in + (size_t)b * 3 * 128 * 128 + (2 * y) * 128 + 2 * x;

    float pch[27];
#pragma unroll
    for (int ci = 0; ci < 3; ++ci) {
        const float* ip = ib + ci * 128 * 128;
        float2 a0 = *(const float2*)(ip);
        float2 a1 = *(const float2*)(ip + 128);
        float2 a2 = *(const float2*)(ip + 256);
        pch[ci * 9 + 0] = a0.x; pch[ci * 9 + 1] = a0.y; pch[ci * 9 + 2] = ip[2];
        pch[ci * 9 + 3] = a1.x; pch[ci * 9 + 4] = a1.y; pch[ci * 9 + 5] = ip[130];
        pch[ci * 9 + 6] = a2.x; pch[ci * 9 + 7] = a2.y; pch[ci * 9 + 8] = ip[258];
    }

    float acc[64];
#pragma unroll
    for (int u = 0; u < 64; ++u) acc[u] = bias[u];

#pragma unroll 1
    for (int ci = 0; ci < 3; ++ci) {
        const float* wc = wt + ci * 576;
#pragma unroll
        for (int u = 0; u < 64; ++u)
#pragma unroll
            for (int k = 0; k < 9; ++k)
                acc[u] = fmaf(pch[ci * 9 + k], wc[u * 9 + k], acc[u]);
    }

    if (active) {
#pragma unroll
        for (int u = 0; u < 64; ++u)
            out[((size_t)(b * 64 + u) * 63 + y) * 64 + x] = acc[u];
    }
}

// ---------------------------------------------------------------- conv2: 64->64, global_load_lds staged
// grid (32 b, 4 co-groups of 16, 4 y-tiles of 8). Block 256 = 4 waves; wave w
// DMAs channel (chunk*4+w): rows 2y0..2y0+16 are 1088 CONTIGUOUS floats in h1
// (rs 64) -> 5 global_load_lds dwordx4 instrs (1024B/instr, zero VALU, zero VGPR).
// __syncthreads' implicit vmcnt(0) drain IS the DMA wait. Compute: 6 ds_reads
// + 144 FMA per ci (LDS read scheduling is compiler-good per m97 evidence).
__global__ __launch_bounds__(256) void conv2_kernel(
    const float* __restrict__ in, const float* __restrict__ wt,
    const float* __restrict__ bias, float* __restrict__ out)
{
    __shared__ float tile[4][1088];      // 4 ch x 17 rows x 64 = 17.4 KB
    const int b   = blockIdx.x;
    const int co0 = blockIdx.y * 16;
    const int y0  = blockIdx.z * 8;
    const int t   = threadIdx.x;
    const int wv  = t >> 6, lane = t & 63;

    const int ty_r = t >> 5, tx_r = t & 31;
    const bool active = (tx_r < 31) && (y0 + ty_r < 31);
    const int ty = active ? ty_r : 0;
    const int tx = active ? tx_r : 0;

    float acc[16];
#pragma unroll
    for (int u = 0; u < 16; ++u) acc[u] = bias[co0 + u];

#pragma unroll 1
    for (int k = 0; k < 16; ++k) {
        // ---- DMA chunk k: wave wv stages channel k*4+wv (last tile reads <=2
        // rows past the plane; lands in h2 region of ws -> safe, consumed only
        // by inactive rows)
        {
            const float* src = in + (size_t)(b * 64 + k * 4 + wv) * 4032 + 2 * y0 * 64;
            float* dst = &tile[wv][0];
#pragma unroll
            for (int i = 0; i < 4; ++i)
                gload16(src + i * 256 + lane * 4, dst + i * 256);
            if (lane < 16)
                gload16(src + 1024 + lane * 4, dst + 1024);
        }
        __syncthreads();                 // drains DMA (vmcnt 0) + barrier

#pragma unroll
        for (int ch = 0; ch < 4; ++ch) {
            const float* tp = &tile[ch][2 * ty * 64 + 2 * tx];
            float2 a0 = *(const float2*)(tp);
            float2 a1 = *(const float2*)(tp + 64);
            float2 a2 = *(const float2*)(tp + 128);
            const float pch[9] = {a0.x, a0.y, tp[2], a1.x, a1.y, tp[66],
                                  a2.x, a2.y, tp[130]};
            const float* wc = wt + (size_t)(k * 4 + ch) * 576 + co0 * 9;
#pragma unroll
            for (int u = 0; u < 16; ++u)
#pragma unroll
                for (int j = 0; j < 9; ++j)
                    acc[u] = fmaf(pch[j], wc[u * 9 + j], acc[u]);
        }
        __syncthreads();                 // protect tile before next DMA
    }

    if (active) {
#pragma unroll
        for (int u = 0; u < 16; ++u)
            out[((size_t)(b * 64 + co0 + u) * 31 + (y0 + ty)) * 32 + tx] = acc[u];
    }
}

// ---------------------------------------------------------------- conv3: 64->64, global_load_lds staged
// grid (32 b, 8 co-groups of 8). Whole 31x32 input plane per channel staged
// (992 contiguous floats = 3 full + 1 partial DMA instr per wave).
__global__ __launch_bounds__(256) void conv3_kernel(
    const float* __restrict__ in, const float* __restrict__ wt,
    const float* __restrict__ bias, float* __restrict__ out)
{
    __shared__ float tile[4][992];       // 4 ch x 31 rows x 32 = 15.9 KB
    const int b   = blockIdx.x;
    const int co0 = blockIdx.y * 8;
    const int t   = threadIdx.x;
    const int wv  = t >> 6, lane = t & 63;

    const int ty_r = t >> 4, tx_r = t & 15;
    const bool active = (tx_r < 15) && (ty_r < 15);
    const int ty = active ? ty_r : 0;
    const int tx = active ? tx_r : 0;

    float acc[8];
#pragma unroll
    for (int u = 0; u < 8; ++u) acc[u] = bias[co0 + u];

#pragma unroll 1
    for (int k = 0; k < 16; ++k) {
        {
            const float* src = in + (size_t)(b * 64 + k * 4 + wv) * 992;
            float* dst = &tile[wv][0];
#pragma unroll
            for (int i = 0; i < 3; ++i)
                gload16(src + i * 256 + lane * 4, dst + i * 256);
            if (lane < 56)
                gload16(src + 768 + lane * 4, dst + 768);
        }
        __syncthreads();

#pragma unroll
        for (int ch = 0; ch < 4; ++ch) {
            const float* tp = &tile[ch][2 * ty * 32 + 2 * tx];
            float2 a0 = *(const float2*)(tp);
            float2 a1 = *(const float2*)(tp + 32);
            float2 a2 = *(const float2*)(tp + 64);
            const float pch[9] = {a0.x, a0.y, tp[2], a1.x, a1.y, tp[34],
                                  a2.x, a2.y, tp[66]};
            const float* wc = wt + (size_t)(k * 4 + ch) * 576 + co0 * 9;
#pragma unroll
            for (int u = 0; u < 8; ++u)
#pragma unroll
                for (int j = 0; j < 9; ++j)
                    acc[u] = fmaf(pch[j], wc[u * 9 + j], acc[u]);
        }
        __syncthreads();
    }

    if (active) {
#pragma unroll
        for (int u = 0; u < 8; ++u)
            out[((size_t)(b * 64 + co0 + u) * 15 + ty) * 16 + tx] = acc[u];
    }
}

// ---------------------------------------------------------------- conv4: direct (tiny, L2-resident input)
template <int CIN, int HIN, int RSIN, int HOUT, int WOUT, int RSOUT, int G, int BLOCK>
__global__ __launch_bounds__(BLOCK, 8) void conv_kernel(
    const float* __restrict__ in, const float* __restrict__ wt,
    const float* __restrict__ bias, float* __restrict__ out)
{
    const int b   = blockIdx.x;
    const int co0 = blockIdx.y * G;
    const int t   = threadIdx.x;
    const int px  = blockIdx.z * BLOCK + t;
    const bool active = px < HOUT * WOUT;
    const int p = active ? px : 0;
    const int y = p / WOUT, x = p % WOUT;

    const float* ib = in + (size_t)b * CIN * HIN * RSIN + (2 * y) * RSIN + 2 * x;

    float acc[G];
#pragma unroll
    for (int u = 0; u < G; ++u) acc[u] = bias[co0 + u];

#pragma unroll 1
    for (int ci = 0; ci < CIN; ++ci) {
        const float* ip = ib + (size_t)ci * (HIN * RSIN);
        float2 a0 = *(const float2*)(ip);
        float2 a1 = *(const float2*)(ip + RSIN);
        float2 a2 = *(const float2*)(ip + 2 * RSIN);
        const float pch[9] = {a0.x, a0.y, ip[2], a1.x, a1.y, ip[RSIN + 2],
                              a2.x, a2.y, ip[2 * RSIN + 2]};
        const float* wc = wt + ci * 576 + co0 * 9;
#pragma unroll
        for (int u = 0; u < G; ++u)
#pragma unroll
            for (int j = 0; j < 9; ++j)
                acc[u] = fmaf(pch[j], wc[u * 9 + j], acc[u]);
    }

    if (active) {
#pragma unroll
        for (int u = 0; u < G; ++u)
            out[((size_t)(b * 64 + co0 + u) * HOUT + y) * RSOUT + x] = acc[u];
    }
}

// ---------------------------------------------------------------- stats: raw h -> per-split partial [8][64][2]
template <int PLANE_PAD, int RSOUT, int BPS>
__global__ __launch_bounds__(256) void stats_kernel(
    const float* __restrict__ h, float* __restrict__ partial)
{
    const int c = blockIdx.x, sp = blockIdx.y, t = threadIdx.x;
    constexpr int N4 = PLANE_PAD / 4;
    constexpr int Q  = RSOUT / 4;
    float s = 0.f, q = 0.f;
    for (int bb = sp * BPS; bb < (sp + 1) * BPS; ++bb) {
        const float4* pp = (const float4*)(h + (size_t)(bb * 64 + c) * PLANE_PAD);
        for (int i = t; i < N4; i += 256) {
            float4 v = pp[i];
            float w_ = ((i & (Q - 1)) == (Q - 1)) ? 0.f : v.w;
            s += v.x + v.y + v.z + w_;
            q += v.x * v.x + v.y * v.y + v.z * v.z + w_ * w_;
        }
    }
    __shared__ float ls[4], lq[4];
    const int lane = t & 63, wv = t >> 6;
#pragma unroll
    for (int off = 32; off > 0; off >>= 1) {
        s += __shfl_down(s, off);
        q += __shfl_down(q, off);
    }
    if (lane == 0) { ls[wv] = s; lq[wv] = q; }
    __syncthreads();
    if (t == 0) {
        s = ls[0] + ls[1] + ls[2] + ls[3];
        q = lq[0] + lq[1] + lq[2] + lq[3];
        partial[(sp * 64 + c) * 2 + 0] = s;
        partial[(sp * 64 + c) * 2 + 1] = q;
    }
}

// ---------------------------------------------------------------- bn + elu (in place, float4)
template <int PLANE_PAD, int NREAL>
__global__ __launch_bounds__(256) void bnelu_kernel(
    float* __restrict__ h, const float* __restrict__ partial,
    const float* __restrict__ g, const float* __restrict__ be)
{
    __shared__ float sa[64], sb[64];
    const int t = threadIdx.x;
    if (t < 64) {
        float s = 0.f, q = 0.f;
#pragma unroll
        for (int k = 0; k < 8; ++k) {
            s += partial[(k * 64 + t) * 2 + 0];
            q += partial[(k * 64 + t) * 2 + 1];
        }
        constexpr float invN = 1.f / (float)(BATCH * NREAL);
        float m = s * invN;
        float var = fmaf(q, invN, -m * m);
        float a = g[t] * rsqrtf(var + 1e-5f);
        sa[t] = a;
        sb[t] = fmaf(-a, m, be[t]);
    }
    __syncthreads();

    const long long total4 = (long long)BATCH * 64 * PLANE_PAD / 4;
    float4* h4 = (float4*)h;
    for (long long i4 = (long long)blockIdx.x * 256 + t; i4 < total4;
         i4 += (long long)gridDim.x * 256) {
        int c = (int)((i4 * 4 / PLANE_PAD) & 63);
        float a = sa[c], bb = sb[c];
        float4 v = h4[i4];
        v.x = eluf(fmaf(a, v.x, bb));
        v.y = eluf(fmaf(a, v.y, bb));
        v.z = eluf(fmaf(a, v.z, bb));
        v.w = eluf(fmaf(a, v.w, bb));
        h4[i4] = v;
    }
}

// ---------------------------------------------------------------- head: bn4+elu + 1x1 convs + params
__global__ __launch_bounds__(256) void head_kernel(
    const float* __restrict__ x4, const float* __restrict__ partial4,
    const float* __restrict__ g4, const float* __restrict__ be4,
    const float* __restrict__ wp, const float* __restrict__ bp,
    const float* __restrict__ wz, const float* __restrict__ bz,
    const float* __restrict__ eps_scale, const float* __restrict__ eps_shift,
    float* __restrict__ params)
{
    __shared__ float xs[64 * 49];
    __shared__ float fe[64 * 49];
    __shared__ float zz[11 * 49];
    __shared__ float ha[64], hb[64];
    const int b = blockIdx.x, t = threadIdx.x;

    if (t < 64) {
        float s = 0.f, q = 0.f;
#pragma unroll
        for (int k = 0; k < 8; ++k) {
            s += partial4[(k * 64 + t) * 2 + 0];
            q += partial4[(k * 64 + t) * 2 + 1];
        }
        constexpr float invN = 1.f / (float)(BATCH * 49);
        float m = s * invN;
        float var = fmaf(q, invN, -m * m);
        float a = g4[t] * rsqrtf(var + 1e-5f);
        ha[t] = a;
        hb[t] = fmaf(-a, m, be4[t]);
    }
    __syncthreads();

    for (int i = t; i < 64 * 49; i += 256) {
        int c = i / 49, p = i % 49;
        float v = x4[(size_t)b * 64 * 56 + c * 56 + (p / 7) * 8 + (p % 7)];
        xs[i] = eluf(fmaf(ha[c], v, hb[c]));
    }
    __syncthreads();

    for (int i = t; i < 64 * 49; i += 256) {
        int co = i / 49, p = i % 49;
        float a = bp[co];
        for (int ci = 0; ci < 64; ++ci) a = fmaf(xs[ci * 49 + p], wp[co * 64 + ci], a);
        fe[i] = eluf(a);
    }
    __syncthreads();

    for (int i = t; i < 11 * 49; i += 256) {
        int co = i / 49, p = i % 49;
        float a = bz[co];
        for (int ci = 0; ci < 64; ++ci) a = fmaf(fe[ci * 49 + p], wz[co * 64 + ci], a);
        zz[i] = a;
    }
    __syncthreads();

    if (t < 49) {
        const int i = t / 7, j = t % 7;
        float es0 = eps_scale[((size_t)b * 49 + t) * 2 + 0];
        float es1 = eps_scale[((size_t)b * 49 + t) * 2 + 1];
        float eh0 = eps_shift[((size_t)b * 49 + t) * 2 + 0];
        float eh1 = eps_shift[((size_t)b * 49 + t) * 2 + 1];
        float zs0 = zz[3 * 49 + t] + softplusf(zz[5 * 49 + t]) * es0;
        float zs1 = zz[4 * 49 + t] + softplusf(zz[6 * 49 + t]) * es1;
        float zh0 = zz[7 * 49 + t] + softplusf(zz[9 * 49 + t]) * eh0;
        float zh1 = zz[8 * 49 + t] + softplusf(zz[10 * 49 + t]) * eh1;
        float th = sigmoidf(zs0) * 0.25f;
        float tw = sigmoidf(zs1) * 0.25f;
        float tx = ((float)i / 7.0f + sigmoidf(zh0) / 7.0f) * 2.f - 1.f;
        float ty = ((float)j / 7.0f + sigmoidf(zh1) / 7.0f) * 2.f - 1.f;
        float4* pp = (float4*)params;
        pp[b * 49 + t] = make_float4(th, tw, tx, ty);
    }
}

// ---------------------------------------------------------------- bilinear glimpse sampler
__device__ __forceinline__ float tap(const float* __restrict__ im, int yy, int xx) {
    bool ok = (xx >= 0) & (xx < 128) & (yy >= 0) & (yy < 128);
    int yc = min(max(yy, 0), 127);
    int xc = min(max(xx, 0), 127);
    return ok ? im[yc * 128 + xc] : 0.f;
}

__global__ __launch_bounds__(256) void sampler_kernel(
    const float* __restrict__ img, const float* __restrict__ params,
    float* __restrict__ out)
{
    const int bk = blockIdx.x;       // b*49 + k
    const int b  = bk / 49;
    const float4 pr = ((const float4*)params)[bk];
    const float th = pr.x, tw = pr.y, tx = pr.z, ty = pr.w;

    for (int idx = threadIdx.x; idx < 3072; idx += 256) {
        const int c  = idx >> 10;
        const int gy = (idx >> 5) & 31;
        const int gx = idx & 31;
        float xb = (2.f * gx + 1.f) / 32.f - 1.f;
        float yb = (2.f * gy + 1.f) / 32.f - 1.f;
        float ixn = fmaf(tw, xb, ty);
        float iyn = fmaf(th, yb, tx);
        float px = ((ixn + 1.f) * 128.f - 1.f) * 0.5f;
        float py = ((iyn + 1.f) * 128.f - 1.f) * 0.5f;
        float x0f = floorf(px), y0f = floorf(py);
        float wx = px - x0f, wy = py - y0f;
        int x0 = (int)x0f, y0 = (int)y0f;
        const float* im = img + ((size_t)b * 3 + c) * 16384;
        float v00 = tap(im, y0, x0);
        float v01 = tap(im, y0, x0 + 1);
        float v10 = tap(im, y0 + 1, x0);
        float v11 = tap(im, y0 + 1, x0 + 1);
        float r = v00 * (1.f - wy) * (1.f - wx) + v01 * (1.f - wy) * wx +
                  v10 * wy * (1.f - wx)        + v11 * wy * wx;
        out[(size_t)bk * 3072 + idx] = r;
    }
}

// ---------------------------------------------------------------- launch
extern "C" void kernel_launch(void* const* d_in, const int* in_sizes, int n_in,
                              void* d_out, int out_size, void* d_ws, size_t ws_size,
                              hipStream_t stream)
{
    const float* img       = (const float*)d_in[0];
    const float* eps_scale = (const float*)d_in[1];
    const float* eps_shift = (const float*)d_in[2];
    const float* w1 = (const float*)d_in[3],  *b1 = (const float*)d_in[4];
    const float* g1 = (const float*)d_in[5],  *be1 = (const float*)d_in[6];
    const float* w2 = (const float*)d_in[7],  *b2 = (const float*)d_in[8];
    const float* g2 = (const float*)d_in[9],  *be2 = (const float*)d_in[10];
    const float* w3 = (const float*)d_in[11], *b3 = (const float*)d_in[12];
    const float* g3 = (const float*)d_in[13], *be3 = (const float*)d_in[14];
    const float* w4 = (const float*)d_in[15], *b4 = (const float*)d_in[16];
    const float* g4 = (const float*)d_in[17], *be4 = (const float*)d_in[18];
    const float* wp = (const float*)d_in[19], *bp = (const float*)d_in[20];
    const float* wz = (const float*)d_in[21], *bz = (const float*)d_in[22];

    float* ws     = (float*)d_ws;
    float* params = ws;                  // 6272
    float* part1  = ws + 8192;           // [8][64][2] each
    float* part2  = ws + 9216;
    float* part3  = ws + 10240;
    float* part4  = ws + 11264;
    float* wt1    = ws + 16384;          // 1728
    float* wt2    = ws + 20480;          // 36864
    float* wt3    = ws + 57344;          // 36864
    float* wt4    = ws + 94208;          // 36864
    float* h1     = ws + 131072;                     // [32][64][63][64]
    float* h2     = h1 + (size_t)32 * 64 * 63 * 64;  // [32][64][31][32]
    float* h3     = h2 + (size_t)32 * 64 * 31 * 32;  // [32][64][15][16]
    float* h4     = h3 + (size_t)32 * 64 * 15 * 16;  // [32][64][7][8]

    float* outp = (float*)d_out;

    // all 4 weight transposes, one launch
    wtrans_kernel<<<dim3(144, 4), 256, 0, stream>>>(w1, wt1, w2, wt2, w3, wt3, w4, wt4);

    // conv1: G=64. h1 RAW.
    conv1_kernel<<<dim3(32, 1, 16), 256, 0, stream>>>(img, wt1, b1, h1);
    stats_kernel<63 * 64, 64, 4><<<dim3(64, 8), 256, 0, stream>>>(h1, part1);
    bnelu_kernel<63 * 64, 63 * 63><<<2048, 256, 0, stream>>>(h1, part1, g1, be1);

    // conv2: LDS-DMA staged. h2 RAW.
    conv2_kernel<<<dim3(32, 4, 4), 256, 0, stream>>>(h1, wt2, b2, h2);
    stats_kernel<31 * 32, 32, 4><<<dim3(64, 8), 256, 0, stream>>>(h2, part2);
    bnelu_kernel<31 * 32, 31 * 31><<<1984, 256, 0, stream>>>(h2, part2, g2, be2);

    // conv3: LDS-DMA staged, whole-plane. h3 RAW.
    conv3_kernel<<<dim3(32, 8), 256, 0, stream>>>(h2, wt3, b3, h3);
    stats_kernel<15 * 16, 16, 4><<<dim3(64, 8), 256, 0, stream>>>(h3, part3);
    bnelu_kernel<15 * 16, 15 * 15><<<480, 256, 0, stream>>>(h3, part3, g3, be3);

    // conv4: direct. h4 RAW.
    conv_kernel<64, 15, 16, 7, 7, 8, 8, 64>
        <<<dim3(32, 8, 1), 64, 0, stream>>>(h3, wt4, b4, h4);
    stats_kernel<7 * 8, 8, 4><<<dim3(64, 8), 256, 0, stream>>>(h4, part4);

    // head fuses bn4+elu
    head_kernel<<<32, 256, 0, stream>>>(h4, part4, g4, be4, wp, bp, wz, bz,
                                        eps_scale, eps_shift, params);

    sampler_kernel<<<1568, 256, 0, stream>>>(img, params, outp);
}

// Round 13
// 194.458 us; speedup vs baseline: 1.7113x; 1.7113x over previous
//
#include <hip/hip_runtime.h>
#include <math.h>

#define BATCH 32

// ---------------------------------------------------------------- utilities
__device__ __forceinline__ float eluf(float v) { return v > 0.f ? v : expm1f(v); }
__device__ __forceinline__ float softplusf(float x) {
    return fmaxf(x, 0.f) + log1pf(expf(-fabsf(x)));
}
__device__ __forceinline__ float sigmoidf(float x) { return 1.f / (1.f + expf(-x)); }

// ---------------------------------------------------------------- weight transpose (all 4 layers, 1 launch)
// w[co][ci][3][3] -> wt[ci][co][9] (R11-verified win: contiguous s_load streams)
__global__ __launch_bounds__(256) void wtrans_kernel(
    const float* __restrict__ w1, float* __restrict__ wt1,
    const float* __restrict__ w2, float* __restrict__ wt2,
    const float* __restrict__ w3, float* __restrict__ wt3,
    const float* __restrict__ w4, float* __restrict__ wt4)
{
    const int idx = blockIdx.x * 256 + threadIdx.x;
    const float* w; float* wt; int cin;
    switch (blockIdx.y) {
        case 0:  w = w1; wt = wt1; cin = 3;  break;
        case 1:  w = w2; wt = wt2; cin = 64; break;
        case 2:  w = w3; wt = wt3; cin = 64; break;
        default: w = w4; wt = wt4; cin = 64; break;
    }
    if (idx < cin * 576) {
        const int k = idx % 9, rest = idx / 9;
        const int co = rest & 63, ci = rest >> 6;
        wt[idx] = w[(co * cin + ci) * 9 + k];
    }
}

// ---------------------------------------------------------------- conv1: 3->64, G=64 (R11-exact; escaped the 60us wall)
__global__ __launch_bounds__(256, 2) void conv1_kernel(
    const float* __restrict__ in, const float* __restrict__ wt,
    const float* __restrict__ bias, float* __restrict__ out)
{
    const int b  = blockIdx.x;
    const int t  = threadIdx.x;
    const int px = blockIdx.z * 256 + t;
    const bool active = px < 63 * 63;
    const int p = active ? px : 0;
    const int y = p / 63, x = p % 63;

    const float* ib = in + (size_t)b * 3 * 128 * 128 + (2 * y) * 128 + 2 * x;

    float pch[27];
#pragma unroll
    for (int ci = 0; ci < 3; ++ci) {
        const float* ip = ib + ci * 128 * 128;
        float2 a0 = *(const float2*)(ip);
        float2 a1 = *(const float2*)(ip + 128);
        float2 a2 = *(const float2*)(ip + 256);
        pch[ci * 9 + 0] = a0.x; pch[ci * 9 + 1] = a0.y; pch[ci * 9 + 2] = ip[2];
        pch[ci * 9 + 3] = a1.x; pch[ci * 9 + 4] = a1.y; pch[ci * 9 + 5] = ip[130];
        pch[ci * 9 + 6] = a2.x; pch[ci * 9 + 7] = a2.y; pch[ci * 9 + 8] = ip[258];
    }

    float acc[64];
#pragma unroll
    for (int u = 0; u < 64; ++u) acc[u] = bias[u];

#pragma unroll 1
    for (int ci = 0; ci < 3; ++ci) {
        const float* wc = wt + ci * 576;
#pragma unroll
        for (int u = 0; u < 64; ++u)
#pragma unroll
            for (int k = 0; k < 9; ++k)
                acc[u] = fmaf(pch[ci * 9 + k], wc[u * 9 + k], acc[u]);
    }

    if (active) {
#pragma unroll
        for (int u = 0; u < 64; ++u)
            out[((size_t)(b * 64 + u) * 63 + y) * 64 + x] = acc[u];
    }
}

// ---------------------------------------------------------------- conv 3x3 s2 direct, transposed wt, ci-PAIRED loads
// 12 independent loads issued per 2-ci step before any FMA consumes them;
// launch_bounds gives 128-VGPR headroom so the compiler can keep both patches
// live (R11: 64-cap -> VGPR=16 -> serialized loads -> 70% stall).
template <int CIN, int HIN, int RSIN, int HOUT, int WOUT, int RSOUT, int G, int BLOCK, int WPE>
__global__ __launch_bounds__(BLOCK, WPE) void conv_kernel(
    const float* __restrict__ in, const float* __restrict__ wt,
    const float* __restrict__ bias, float* __restrict__ out)
{
    const int b   = blockIdx.x;
    const int co0 = blockIdx.y * G;
    const int t   = threadIdx.x;
    const int px  = blockIdx.z * BLOCK + t;
    const bool active = px < HOUT * WOUT;
    const int p = active ? px : 0;
    const int y = p / WOUT, x = p % WOUT;

    const float* ib = in + (size_t)b * CIN * HIN * RSIN + (2 * y) * RSIN + 2 * x;

    float acc[G];
#pragma unroll
    for (int u = 0; u < G; ++u) acc[u] = bias[co0 + u];

#pragma unroll 1
    for (int ci = 0; ci < CIN; ci += 2) {
        const float* ipA = ib + (size_t)ci * (HIN * RSIN);
        const float* ipB = ipA + (HIN * RSIN);
        // 12 independent loads, all issued before first use
        float2 aA0 = *(const float2*)(ipA);
        float2 aA1 = *(const float2*)(ipA + RSIN);
        float2 aA2 = *(const float2*)(ipA + 2 * RSIN);
        float  cA0 = ipA[2], cA1 = ipA[RSIN + 2], cA2 = ipA[2 * RSIN + 2];
        float2 aB0 = *(const float2*)(ipB);
        float2 aB1 = *(const float2*)(ipB + RSIN);
        float2 aB2 = *(const float2*)(ipB + 2 * RSIN);
        float  cB0 = ipB[2], cB1 = ipB[RSIN + 2], cB2 = ipB[2 * RSIN + 2];

        const float pA[9] = {aA0.x, aA0.y, cA0, aA1.x, aA1.y, cA1, aA2.x, aA2.y, cA2};
        const float pB[9] = {aB0.x, aB0.y, cB0, aB1.x, aB1.y, cB1, aB2.x, aB2.y, cB2};

        const float* wcA = wt + (size_t)ci * 576 + co0 * 9;
        const float* wcB = wcA + 576;
#pragma unroll
        for (int u = 0; u < G; ++u)
#pragma unroll
            for (int j = 0; j < 9; ++j)
                acc[u] = fmaf(pA[j], wcA[u * 9 + j], acc[u]);
#pragma unroll
        for (int u = 0; u < G; ++u)
#pragma unroll
            for (int j = 0; j < 9; ++j)
                acc[u] = fmaf(pB[j], wcB[u * 9 + j], acc[u]);
    }

    if (active) {
#pragma unroll
        for (int u = 0; u < G; ++u)
            out[((size_t)(b * 64 + co0 + u) * HOUT + y) * RSOUT + x] = acc[u];
    }
}

// ---------------------------------------------------------------- stats: raw h -> per-split partial [8][64][2]
template <int PLANE_PAD, int RSOUT, int BPS>
__global__ __launch_bounds__(256) void stats_kernel(
    const float* __restrict__ h, float* __restrict__ partial)
{
    const int c = blockIdx.x, sp = blockIdx.y, t = threadIdx.x;
    constexpr int N4 = PLANE_PAD / 4;
    constexpr int Q  = RSOUT / 4;
    float s = 0.f, q = 0.f;
    for (int bb = sp * BPS; bb < (sp + 1) * BPS; ++bb) {
        const float4* pp = (const float4*)(h + (size_t)(bb * 64 + c) * PLANE_PAD);
        for (int i = t; i < N4; i += 256) {
            float4 v = pp[i];
            float w_ = ((i & (Q - 1)) == (Q - 1)) ? 0.f : v.w;
            s += v.x + v.y + v.z + w_;
            q += v.x * v.x + v.y * v.y + v.z * v.z + w_ * w_;
        }
    }
    __shared__ float ls[4], lq[4];
    const int lane = t & 63, wv = t >> 6;
#pragma unroll
    for (int off = 32; off > 0; off >>= 1) {
        s += __shfl_down(s, off);
        q += __shfl_down(q, off);
    }
    if (lane == 0) { ls[wv] = s; lq[wv] = q; }
    __syncthreads();
    if (t == 0) {
        s = ls[0] + ls[1] + ls[2] + ls[3];
        q = lq[0] + lq[1] + lq[2] + lq[3];
        partial[(sp * 64 + c) * 2 + 0] = s;
        partial[(sp * 64 + c) * 2 + 1] = q;
    }
}

// ---------------------------------------------------------------- bn + elu (in place, float4)
template <int PLANE_PAD, int NREAL>
__global__ __launch_bounds__(256) void bnelu_kernel(
    float* __restrict__ h, const float* __restrict__ partial,
    const float* __restrict__ g, const float* __restrict__ be)
{
    __shared__ float sa[64], sb[64];
    const int t = threadIdx.x;
    if (t < 64) {
        float s = 0.f, q = 0.f;
#pragma unroll
        for (int k = 0; k < 8; ++k) {
            s += partial[(k * 64 + t) * 2 + 0];
            q += partial[(k * 64 + t) * 2 + 1];
        }
        constexpr float invN = 1.f / (float)(BATCH * NREAL);
        float m = s * invN;
        float var = fmaf(q, invN, -m * m);
        float a = g[t] * rsqrtf(var + 1e-5f);
        sa[t] = a;
        sb[t] = fmaf(-a, m, be[t]);
    }
    __syncthreads();

    const long long total4 = (long long)BATCH * 64 * PLANE_PAD / 4;
    float4* h4 = (float4*)h;
    for (long long i4 = (long long)blockIdx.x * 256 + t; i4 < total4;
         i4 += (long long)gridDim.x * 256) {
        int c = (int)((i4 * 4 / PLANE_PAD) & 63);
        float a = sa[c], bb = sb[c];
        float4 v = h4[i4];
        v.x = eluf(fmaf(a, v.x, bb));
        v.y = eluf(fmaf(a, v.y, bb));
        v.z = eluf(fmaf(a, v.z, bb));
        v.w = eluf(fmaf(a, v.w, bb));
        h4[i4] = v;
    }
}

// ---------------------------------------------------------------- head: bn4+elu + 1x1 convs + params
__global__ __launch_bounds__(256) void head_kernel(
    const float* __restrict__ x4, const float* __restrict__ partial4,
    const float* __restrict__ g4, const float* __restrict__ be4,
    const float* __restrict__ wp, const float* __restrict__ bp,
    const float* __restrict__ wz, const float* __restrict__ bz,
    const float* __restrict__ eps_scale, const float* __restrict__ eps_shift,
    float* __restrict__ params)
{
    __shared__ float xs[64 * 49];
    __shared__ float fe[64 * 49];
    __shared__ float zz[11 * 49];
    __shared__ float ha[64], hb[64];
    const int b = blockIdx.x, t = threadIdx.x;

    if (t < 64) {
        float s = 0.f, q = 0.f;
#pragma unroll
        for (int k = 0; k < 8; ++k) {
            s += partial4[(k * 64 + t) * 2 + 0];
            q += partial4[(k * 64 + t) * 2 + 1];
        }
        constexpr float invN = 1.f / (float)(BATCH * 49);
        float m = s * invN;
        float var = fmaf(q, invN, -m * m);
        float a = g4[t] * rsqrtf(var + 1e-5f);
        ha[t] = a;
        hb[t] = fmaf(-a, m, be4[t]);
    }
    __syncthreads();

    for (int i = t; i < 64 * 49; i += 256) {
        int c = i / 49, p = i % 49;
        float v = x4[(size_t)b * 64 * 56 + c * 56 + (p / 7) * 8 + (p % 7)];
        xs[i] = eluf(fmaf(ha[c], v, hb[c]));
    }
    __syncthreads();

    for (int i = t; i < 64 * 49; i += 256) {
        int co = i / 49, p = i % 49;
        float a = bp[co];
        for (int ci = 0; ci < 64; ++ci) a = fmaf(xs[ci * 49 + p], wp[co * 64 + ci], a);
        fe[i] = eluf(a);
    }
    __syncthreads();

    for (int i = t; i < 11 * 49; i += 256) {
        int co = i / 49, p = i % 49;
        float a = bz[co];
        for (int ci = 0; ci < 64; ++ci) a = fmaf(fe[ci * 49 + p], wz[co * 64 + ci], a);
        zz[i] = a;
    }
    __syncthreads();

    if (t < 49) {
        const int i = t / 7, j = t % 7;
        float es0 = eps_scale[((size_t)b * 49 + t) * 2 + 0];
        float es1 = eps_scale[((size_t)b * 49 + t) * 2 + 1];
        float eh0 = eps_shift[((size_t)b * 49 + t) * 2 + 0];
        float eh1 = eps_shift[((size_t)b * 49 + t) * 2 + 1];
        float zs0 = zz[3 * 49 + t] + softplusf(zz[5 * 49 + t]) * es0;
        float zs1 = zz[4 * 49 + t] + softplusf(zz[6 * 49 + t]) * es1;
        float zh0 = zz[7 * 49 + t] + softplusf(zz[9 * 49 + t]) * eh0;
        float zh1 = zz[8 * 49 + t] + softplusf(zz[10 * 49 + t]) * eh1;
        float th = sigmoidf(zs0) * 0.25f;
        float tw = sigmoidf(zs1) * 0.25f;
        float tx = ((float)i / 7.0f + sigmoidf(zh0) / 7.0f) * 2.f - 1.f;
        float ty = ((float)j / 7.0f + sigmoidf(zh1) / 7.0f) * 2.f - 1.f;
        float4* pp = (float4*)params;
        pp[b * 49 + t] = make_float4(th, tw, tx, ty);
    }
}

// ---------------------------------------------------------------- bilinear glimpse sampler
__device__ __forceinline__ float tap(const float* __restrict__ im, int yy, int xx) {
    bool ok = (xx >= 0) & (xx < 128) & (yy >= 0) & (yy < 128);
    int yc = min(max(yy, 0), 127);
    int xc = min(max(xx, 0), 127);
    return ok ? im[yc * 128 + xc] : 0.f;
}

__global__ __launch_bounds__(256) void sampler_kernel(
    const float* __restrict__ img, const float* __restrict__ params,
    float* __restrict__ out)
{
    const int bk = blockIdx.x;       // b*49 + k
    const int b  = bk / 49;
    const float4 pr = ((const float4*)params)[bk];
    const float th = pr.x, tw = pr.y, tx = pr.z, ty = pr.w;

    for (int idx = threadIdx.x; idx < 3072; idx += 256) {
        const int c  = idx >> 10;
        const int gy = (idx >> 5) & 31;
        const int gx = idx & 31;
        float xb = (2.f * gx + 1.f) / 32.f - 1.f;
        float yb = (2.f * gy + 1.f) / 32.f - 1.f;
        float ixn = fmaf(tw, xb, ty);
        float iyn = fmaf(th, yb, tx);
        float px = ((ixn + 1.f) * 128.f - 1.f) * 0.5f;
        float py = ((iyn + 1.f) * 128.f - 1.f) * 0.5f;
        float x0f = floorf(px), y0f = floorf(py);
        float wx = px - x0f, wy = py - y0f;
        int x0 = (int)x0f, y0 = (int)y0f;
        const float* im = img + ((size_t)b * 3 + c) * 16384;
        float v00 = tap(im, y0, x0);
        float v01 = tap(im, y0, x0 + 1);
        float v10 = tap(im, y0 + 1, x0);
        float v11 = tap(im, y0 + 1, x0 + 1);
        float r = v00 * (1.f - wy) * (1.f - wx) + v01 * (1.f - wy) * wx +
                  v10 * wy * (1.f - wx)        + v11 * wy * wx;
        out[(size_t)bk * 3072 + idx] = r;
    }
}

// ---------------------------------------------------------------- launch
extern "C" void kernel_launch(void* const* d_in, const int* in_sizes, int n_in,
                              void* d_out, int out_size, void* d_ws, size_t ws_size,
                              hipStream_t stream)
{
    const float* img       = (const float*)d_in[0];
    const float* eps_scale = (const float*)d_in[1];
    const float* eps_shift = (const float*)d_in[2];
    const float* w1 = (const float*)d_in[3],  *b1 = (const float*)d_in[4];
    const float* g1 = (const float*)d_in[5],  *be1 = (const float*)d_in[6];
    const float* w2 = (const float*)d_in[7],  *b2 = (const float*)d_in[8];
    const float* g2 = (const float*)d_in[9],  *be2 = (const float*)d_in[10];
    const float* w3 = (const float*)d_in[11], *b3 = (const float*)d_in[12];
    const float* g3 = (const float*)d_in[13], *be3 = (const float*)d_in[14];
    const float* w4 = (const float*)d_in[15], *b4 = (const float*)d_in[16];
    const float* g4 = (const float*)d_in[17], *be4 = (const float*)d_in[18];
    const float* wp = (const float*)d_in[19], *bp = (const float*)d_in[20];
    const float* wz = (const float*)d_in[21], *bz = (const float*)d_in[22];

    float* ws     = (float*)d_ws;
    float* params = ws;                  // 6272
    float* part1  = ws + 8192;           // [8][64][2] each
    float* part2  = ws + 9216;
    float* part3  = ws + 10240;
    float* part4  = ws + 11264;
    float* wt1    = ws + 16384;          // 1728
    float* wt2    = ws + 20480;          // 36864
    float* wt3    = ws + 57344;          // 36864
    float* wt4    = ws + 94208;          // 36864
    float* h1     = ws + 131072;                     // [32][64][63][64]
    float* h2     = h1 + (size_t)32 * 64 * 63 * 64;  // [32][64][31][32]
    float* h3     = h2 + (size_t)32 * 64 * 31 * 32;  // [32][64][15][16]
    float* h4     = h3 + (size_t)32 * 64 * 15 * 16;  // [32][64][7][8]

    float* outp = (float*)d_out;

    wtrans_kernel<<<dim3(144, 4), 256, 0, stream>>>(w1, wt1, w2, wt2, w3, wt3, w4, wt4);

    // conv1: G=64 (R11-exact). h1 RAW.
    conv1_kernel<<<dim3(32, 1, 16), 256, 0, stream>>>(img, wt1, b1, h1);
    stats_kernel<63 * 64, 64, 4><<<dim3(64, 8), 256, 0, stream>>>(h1, part1);
    bnelu_kernel<63 * 64, 63 * 63><<<2048, 256, 0, stream>>>(h1, part1, g1, be1);

    // conv2: G=8, paired loads, 128-VGPR headroom. 1024 blocks = 16 w/CU.
    conv_kernel<64, 63, 64, 31, 31, 32, 8, 256, 4>
        <<<dim3(32, 8, 4), 256, 0, stream>>>(h1, wt2, b2, h2);
    stats_kernel<31 * 32, 32, 4><<<dim3(64, 8), 256, 0, stream>>>(h2, part2);
    bnelu_kernel<31 * 32, 31 * 31><<<1984, 256, 0, stream>>>(h2, part2, g2, be2);

    // conv3: G=2, 1024 blocks = 16 w/CU (fix R11 under-occupancy).
    conv_kernel<64, 31, 32, 15, 15, 16, 2, 256, 4>
        <<<dim3(32, 32, 1), 256, 0, stream>>>(h2, wt3, b3, h3);
    stats_kernel<15 * 16, 16, 4><<<dim3(64, 8), 256, 0, stream>>>(h3, part3);
    bnelu_kernel<15 * 16, 15 * 15><<<480, 256, 0, stream>>>(h3, part3, g3, be3);

    // conv4: G=1, 2048 single-wave blocks = 8 w/CU (fix 1 w/CU).
    conv_kernel<64, 15, 16, 7, 7, 8, 1, 64, 8>
        <<<dim3(32, 64, 1), 64, 0, stream>>>(h3, wt4, b4, h4);
    stats_kernel<7 * 8, 8, 4><<<dim3(64, 8), 256, 0, stream>>>(h4, part4);

    // head fuses bn4+elu
    head_kernel<<<32, 256, 0, stream>>>(h4, part4, g4, be4, wp, bp, wz, bz,
                                        eps_scale, eps_shift, params);

    sampler_kernel<<<1568, 256, 0, stream>>>(img, params, outp);
}